// Round 10
// baseline (21.151 us; speedup 1.0000x reference)
//
#include <hip/hip_runtime.h>
#include <math.h>

// FBPINN: out(x) = sum_k w_k(x)*subnet_k(x) / sum_k w_k(x), x scalar in [0,1].
// Two dispatches:
//  1) build_tables: grid = 512 single-wave blocks; block = (64-pt stretch,
//     slot s in 0..3), subnet k = klo(stretch)+s (block-uniform). The wave
//     stages its subnet's 8.8KB weights into LDS (9 coalesced float4 loads),
//     evaluates the MLP with ds_read_b128 LDS broadcasts, and writes its
//     slot's w*o values to the INTERLEAVED table g[i*4+s]. No atomics, no
//     zero-fill, no __syncthreads. Rationale (R9 PMC math): broadcast
//     ds_reads (~540/wave @ ~12cyc) bound the CU-shared LDS pipe; R9's
//     4-wave blocks put 4 waves on one CU (26K cyc = 10.8us). Single-wave
//     slot-blocks at T=8192 spread the same work 2 waves/CU => ~5.4us.
//  2) eval_lerp: per point, two float4 loads fetch all 8 interleaved table
//     entries; sum of 4 lerps (= lerp of sum); denominator ANALYTIC
//     (<=4 cosine windows of x only). Kernel-boundary coherence.
// Lerp error ~1e-5 at TBL=8192 << 7.3e-3 threshold (bf16 floor 1.95e-3).

#define KSUB 16
#define NW 32
#define TBL 8192
#define NSTRETCH (TBL / 64)   // 128
#define SLOTS 4               // active-k interval width 3.72+16*dx*63 < 4
// LDS layout (floats): W1[1024] W2[1024] W0[32] B0[32] B1[32] B2[32] W3[32]
#define OW1 0
#define OW2 1024
#define OW0 2048
#define OB0 2080
#define OB1 2112
#define OB2 2144
#define OW3 2176
#define LDSF 2208

// tanh(x) = 1 - 2/(exp(2x)+1); v_exp_f32 is exp2 -> scale by 2*log2(e).
static __device__ __forceinline__ float fast_tanh(float v) {
    float e = __builtin_amdgcn_exp2f(v * 2.8853900817779268f);
    return 1.0f - 2.0f * __builtin_amdgcn_rcpf(e + 1.0f);
}

// cos(pi*u), u in [0,1]: v_cos_f32 takes revolutions.
static __device__ __forceinline__ float cos_pi(float u) {
    return __builtin_amdgcn_cosf(0.5f * u);
}

static __device__ __forceinline__ float window_w(float x, int k) {
    const float invTW = 20.0f;  // 1/0.05
    float xmin = (float)k * 0.0625f - 0.06f;
    float xmax = (float)(k + 1) * 0.0625f + 0.06f;
    float up = (x - xmin + 0.025f) * invTW;
    float dn = (xmax + 0.025f - x) * invTW;
    up = fminf(fmaxf(up, 0.0f), 1.0f);
    dn = fminf(fmaxf(dn, 0.0f), 1.0f);
    return 0.25f * (1.0f - cos_pi(up)) * (1.0f - cos_pi(dn));
}

// Active subnets at x: k in (16x-2.36, 16x+1.36) => at most 4, klo..klo+3.
static __device__ __forceinline__ float den_analytic(float xv) {
    int klo = (int)ceilf(16.0f * xv - 2.36f);
    float den = 0.f;
#pragma unroll
    for (int j = 0; j < 4; ++j) {
        int k = klo + j;
        if (k >= 0 && k < KSUB) den += window_w(xv, k);
    }
    return den;
}

// grid = NSTRETCH*SLOTS blocks x 64 threads. Block: stretch = bx>>2,
// slot = bx&3. Writes g[i*4+slot] for its 64 points.
__global__ __launch_bounds__(64) void build_tables(
    const float* __restrict__ W0, const float* __restrict__ B0,
    const float* __restrict__ W1, const float* __restrict__ B1,
    const float* __restrict__ W2, const float* __restrict__ B2,
    const float* __restrict__ W3, const float* __restrict__ B3,
    float* __restrict__ g)
{
    __shared__ float R[LDSF];   // 8.6 KB weight region

    const int lane = threadIdx.x;         // 0..63
    const int str  = blockIdx.x >> 2;
    const int slot = blockIdx.x & 3;
    const int i    = str * 64 + lane;
    const float inv = 1.0f / (float)(TBL - 1);
    const float xg  = (float)i * inv;

    float x_lo = (float)(str * 64) * inv;
    int klo_b = (int)ceilf(16.0f * x_lo - 2.36f);
    const int k  = klo_b + slot;          // block-uniform
    const int kc = min(max(k, 0), KSUB - 1);

    // ---- stage this subnet's weights into LDS (one memory round-trip) ----
    {
        const float4* gW1 = reinterpret_cast<const float4*>(&W1[kc * NW * NW]);
        const float4* gW2 = reinterpret_cast<const float4*>(&W2[kc * NW * NW]);
        float4 t0 = gW1[0 * 64 + lane];
        float4 t1 = gW1[1 * 64 + lane];
        float4 t2 = gW1[2 * 64 + lane];
        float4 t3 = gW1[3 * 64 + lane];
        float4 t4 = gW2[0 * 64 + lane];
        float4 t5 = gW2[1 * 64 + lane];
        float4 t6 = gW2[2 * 64 + lane];
        float4 t7 = gW2[3 * 64 + lane];
        float4 t8;
        const int a = lane >> 3;          // 0..7 (use 0..4)
        const int e = (lane & 7) * 4;
        const float* sp = (a == 0) ? &W0[kc * NW] :
                          (a == 1) ? &B0[kc * NW] :
                          (a == 2) ? &B1[kc * NW] :
                          (a == 3) ? &B2[kc * NW] : &W3[kc * NW];
        if (a < 5) t8 = *reinterpret_cast<const float4*>(&sp[e]);
        *reinterpret_cast<float4*>(&R[OW1 + 0 * 256 + lane * 4]) = t0;
        *reinterpret_cast<float4*>(&R[OW1 + 1 * 256 + lane * 4]) = t1;
        *reinterpret_cast<float4*>(&R[OW1 + 2 * 256 + lane * 4]) = t2;
        *reinterpret_cast<float4*>(&R[OW1 + 3 * 256 + lane * 4]) = t3;
        *reinterpret_cast<float4*>(&R[OW2 + 0 * 256 + lane * 4]) = t4;
        *reinterpret_cast<float4*>(&R[OW2 + 1 * 256 + lane * 4]) = t5;
        *reinterpret_cast<float4*>(&R[OW2 + 2 * 256 + lane * 4]) = t6;
        *reinterpret_cast<float4*>(&R[OW2 + 3 * 256 + lane * 4]) = t7;
        if (a < 5)
            *reinterpret_cast<float4*>(&R[OW0 + a * 32 + e]) = t8;
    }
    // same-wave ds_write -> ds_read ordering handled by lgkmcnt.

    // ---- evaluate subnet kc at this lane's point, weights from LDS ----
    const float INVS = 10.958904109589041f;  // 1/0.09125 (uniform scale)
    float xn = (xg - ((float)kc + 0.5f) * 0.0625f) * INVS;

    float h0[NW], h1[NW];
    // layer 0
#pragma unroll
    for (int o4 = 0; o4 < NW / 4; ++o4) {
        float4 wvv = *reinterpret_cast<const float4*>(&R[OW0 + 4 * o4]);
        float4 bv  = *reinterpret_cast<const float4*>(&R[OB0 + 4 * o4]);
        h0[4 * o4 + 0] = fast_tanh(fmaf(wvv.x, xn, bv.x));
        h0[4 * o4 + 1] = fast_tanh(fmaf(wvv.y, xn, bv.y));
        h0[4 * o4 + 2] = fast_tanh(fmaf(wvv.z, xn, bv.z));
        h0[4 * o4 + 3] = fast_tanh(fmaf(wvv.w, xn, bv.w));
    }
    // layer 1
#pragma unroll
    for (int o = 0; o < NW; ++o) {
        float a0 = R[OB1 + o], a1 = 0.f, a2 = 0.f, a3 = 0.f;
#pragma unroll
        for (int j4 = 0; j4 < NW / 4; ++j4) {
            float4 wvv = *reinterpret_cast<const float4*>(&R[OW1 + o * NW + 4 * j4]);
            a0 = fmaf(wvv.x, h0[4 * j4 + 0], a0);
            a1 = fmaf(wvv.y, h0[4 * j4 + 1], a1);
            a2 = fmaf(wvv.z, h0[4 * j4 + 2], a2);
            a3 = fmaf(wvv.w, h0[4 * j4 + 3], a3);
        }
        h1[o] = fast_tanh((a0 + a1) + (a2 + a3));
    }
    // layer 2
#pragma unroll
    for (int o = 0; o < NW; ++o) {
        float a0 = R[OB2 + o], a1 = 0.f, a2 = 0.f, a3 = 0.f;
#pragma unroll
        for (int j4 = 0; j4 < NW / 4; ++j4) {
            float4 wvv = *reinterpret_cast<const float4*>(&R[OW2 + o * NW + 4 * j4]);
            a0 = fmaf(wvv.x, h1[4 * j4 + 0], a0);
            a1 = fmaf(wvv.y, h1[4 * j4 + 1], a1);
            a2 = fmaf(wvv.z, h1[4 * j4 + 2], a2);
            a3 = fmaf(wvv.w, h1[4 * j4 + 3], a3);
        }
        h0[o] = fast_tanh((a0 + a1) + (a2 + a3));  // reuse h0 as h2
    }
    // layer 3
    float a0 = B3[kc], a1 = 0.f, a2 = 0.f, a3 = 0.f;
#pragma unroll
    for (int j4 = 0; j4 < NW / 4; ++j4) {
        float4 wvv = *reinterpret_cast<const float4*>(&R[OW3 + 4 * j4]);
        a0 = fmaf(wvv.x, h0[4 * j4 + 0], a0);
        a1 = fmaf(wvv.y, h0[4 * j4 + 1], a1);
        a2 = fmaf(wvv.z, h0[4 * j4 + 2], a2);
        a3 = fmaf(wvv.w, h0[4 * j4 + 3], a3);
    }
    float out_o = (a0 + a1) + (a2 + a3);

    float wgt = window_w(xg, kc);
    g[i * 4 + slot] = (k >= 0 && k < KSUB) ? wgt * out_o : 0.0f;
}

static __device__ __forceinline__ float eval_point(
    float xj, const float* __restrict__ g)
{
    const float scaleT = (float)(TBL - 1);
    float t = fminf(fmaxf(xj * scaleT, 0.0f), scaleT);
    int i0 = (int)t;
    if (i0 > TBL - 2) i0 = TBL - 2;
    float f = t - (float)i0;
    float4 a = *reinterpret_cast<const float4*>(&g[i0 * 4]);
    float4 b = *reinterpret_cast<const float4*>(&g[i0 * 4 + 4]);
    float n0 = (a.x + a.y) + (a.z + a.w);
    float n1 = (b.x + b.y) + (b.z + b.w);
    float num = fmaf(f, n1 - n0, n0);
    float den = den_analytic(xj);
    return num * __builtin_amdgcn_rcpf(den + 1e-12f);
}

// float4 lerp pass over the N points.
__global__ void eval_lerp(const float* __restrict__ x,
                          const float* __restrict__ g,
                          float* __restrict__ out, int N)
{
    int idx = blockIdx.x * blockDim.x + threadIdx.x;
    int base = idx * 4;
    if (base + 3 < N) {
        float4 xv = *reinterpret_cast<const float4*>(&x[base]);
        float4 r;
        r.x = eval_point(xv.x, g);
        r.y = eval_point(xv.y, g);
        r.z = eval_point(xv.z, g);
        r.w = eval_point(xv.w, g);
        *reinterpret_cast<float4*>(&out[base]) = r;
    } else {
        for (int j = base; j < N; ++j) out[j] = eval_point(x[j], g);
    }
}

// ---- fallback path (tiny ws only): direct evaluation via global loads ----
static __device__ __forceinline__ float subnet_eval_g(
    float xn, int kc,
    const float* __restrict__ W0, const float* __restrict__ B0,
    const float* __restrict__ W1, const float* __restrict__ B1,
    const float* __restrict__ W2, const float* __restrict__ B2,
    const float* __restrict__ W3, const float* __restrict__ B3)
{
    float h0[NW], h1[NW];
#pragma unroll
    for (int o = 0; o < NW; ++o)
        h0[o] = fast_tanh(fmaf(W0[kc * NW + o], xn, B0[kc * NW + o]));
#pragma unroll
    for (int o = 0; o < NW; ++o) {
        float a = B1[kc * NW + o];
        const float* row = &W1[kc * NW * NW + o * NW];
#pragma unroll
        for (int j = 0; j < NW; ++j) a = fmaf(row[j], h0[j], a);
        h1[o] = fast_tanh(a);
    }
#pragma unroll
    for (int o = 0; o < NW; ++o) {
        float a = B2[kc * NW + o];
        const float* row = &W2[kc * NW * NW + o * NW];
#pragma unroll
        for (int j = 0; j < NW; ++j) a = fmaf(row[j], h1[j], a);
        h0[o] = fast_tanh(a);
    }
    float a = B3[kc];
#pragma unroll
    for (int j = 0; j < NW; ++j) a = fmaf(W3[kc * NW + j], h0[j], a);
    return a;
}

__global__ void direct_eval(
    const float* __restrict__ x,
    const float* __restrict__ W0, const float* __restrict__ B0,
    const float* __restrict__ W1, const float* __restrict__ B1,
    const float* __restrict__ W2, const float* __restrict__ B2,
    const float* __restrict__ W3, const float* __restrict__ B3,
    float* __restrict__ out, int N)
{
    int n = blockIdx.x * blockDim.x + threadIdx.x;
    if (n >= N) return;
    float xv = x[n];
    float num = 0.f, den = 0.f;
    for (int k = 0; k < KSUB; ++k) {
        float w = window_w(xv, k);
        if (w <= 0.0f) continue;
        float xn = (xv - ((float)k + 0.5f) * 0.0625f) * 10.958904109589041f;
        float o = subnet_eval_g(xn, k, W0, B0, W1, B1, W2, B2, W3, B3);
        num += w * o;
        den += w;
    }
    out[n] = num * __builtin_amdgcn_rcpf(den + 1e-12f);
}

extern "C" void kernel_launch(void* const* d_in, const int* in_sizes, int n_in,
                              void* d_out, int out_size, void* d_ws, size_t ws_size,
                              hipStream_t stream) {
    const float* x  = (const float*)d_in[0];
    const float* W0 = (const float*)d_in[1];
    const float* B0 = (const float*)d_in[2];
    const float* W1 = (const float*)d_in[3];
    const float* B1 = (const float*)d_in[4];
    const float* W2 = (const float*)d_in[5];
    const float* B2 = (const float*)d_in[6];
    const float* W3 = (const float*)d_in[7];
    const float* B3 = (const float*)d_in[8];
    float* out = (float*)d_out;
    const int N = in_sizes[0];

    if ((size_t)TBL * 4 * sizeof(float) <= ws_size) {
        float* g = (float*)d_ws;
        build_tables<<<NSTRETCH * SLOTS, 64, 0, stream>>>(
            W0, B0, W1, B1, W2, B2, W3, B3, g);
        int nv = (N + 3) / 4;
        eval_lerp<<<(nv + 255) / 256, 256, 0, stream>>>(x, g, out, N);
    } else {
        direct_eval<<<(N + 255) / 256, 256, 0, stream>>>(
            x, W0, B0, W1, B1, W2, B2, W3, B3, out, N);
    }
}